// Round 7
// baseline (277.780 us; speedup 1.0000x reference)
//
#include <hip/hip_runtime.h>

typedef _Float16 f16;
typedef _Float16 f16x2 __attribute__((ext_vector_type(2)));
typedef _Float16 f16x4 __attribute__((ext_vector_type(4)));

#define VOCAB 100000
#define DIM 128
#define BATCH 262144
#define NEG 5

#define NBLOCK 2048
#define NTHREADS 256

#define TABLE_HALF_BYTES ((size_t)VOCAB * DIM * 2)            // 25.6 MB
#define WS_NEEDED (256 + 2 * TABLE_HALF_BYTES)                // acc + 2 tables

// log(1 + exp(x)); |x| <~ 0.04 here so exp(-|x|) ~ 1: no cancellation risk.
__device__ __forceinline__ float softplus_fast(float x) {
    return fmaxf(x, 0.0f) + __logf(1.0f + __expf(-fabsf(x)));
}

__device__ __forceinline__ float fdot2h(f16x2 a, f16x2 b, float c) {
#if __has_builtin(__builtin_amdgcn_fdot2)
    return __builtin_amdgcn_fdot2(a, b, c, false);
#else
    return c + (float)a[0] * (float)b[0] + (float)a[1] * (float)b[1];
#endif
}

// dot of two 16-half register pairs (2x uint4 each side), fp32 accumulate
__device__ __forceinline__ float dot16h(uint4 a0, uint4 a1, uint4 b0, uint4 b1) {
    union { uint4 u; f16x2 h[4]; } A0, A1, B0, B1;
    A0.u = a0; A1.u = a1; B0.u = b0; B1.u = b1;
    float s0 = 0.0f, s1 = 0.0f;   // two chains for ILP
    #pragma unroll
    for (int i = 0; i < 4; ++i) {
        s0 = fdot2h(A0.h[i], B0.h[i], s0);
        s1 = fdot2h(A1.h[i], B1.h[i], s1);
    }
    return s0 + s1;
}

__global__ void ns_init_kernel(float* acc) {
    acc[0] = 0.0f;
    acc[1] = 0.0f;
}

// ---- streaming fp32 -> fp16 conversion of both tables ----
__global__ __launch_bounds__(256) void ns_convert_kernel(
    const float* __restrict__ iemb, const float* __restrict__ oemb,
    f16* __restrict__ iembH, f16* __restrict__ oembH)
{
    const int n4 = VOCAB * DIM / 4;   // 3.2M float4 per table
    int i = blockIdx.x * blockDim.x + threadIdx.x;
    const int stride = gridDim.x * blockDim.x;
    for (; i < n4; i += stride) {
        float4 a = reinterpret_cast<const float4*>(iemb)[i];
        f16x4 ha = {(f16)a.x, (f16)a.y, (f16)a.z, (f16)a.w};
        reinterpret_cast<f16x4*>(iembH)[i] = ha;
        float4 b = reinterpret_cast<const float4*>(oemb)[i];
        f16x4 hb = {(f16)b.x, (f16)b.y, (f16)b.z, (f16)b.w};
        reinterpret_cast<f16x4*>(oembH)[i] = hb;
    }
}

// ---- fp16 gather loss kernel: R4 schedule (8 lanes/element, batched loads) ----
__global__ __launch_bounds__(NTHREADS) void ns_loss_h_kernel(
    const int* __restrict__ tgt,
    const int* __restrict__ ctx,
    const int* __restrict__ negw,
    const f16* __restrict__ iembH,
    const f16* __restrict__ oembH,
    float* __restrict__ acc)
{
    const int tid = threadIdx.x;
    const int r   = tid & 7;        // lane within 8-lane group
    const int grp = tid >> 3;       // 32 groups per block
    const int e0  = blockIdx.x * 32 + grp;
    const int estride = gridDim.x * 32;

    float pos_acc = 0.0f, neg_acc = 0.0f;

    for (int e = e0; e < BATCH; e += estride) {
        const int tw = tgt[e];
        const int cw = ctx[e];

        // fp16 row = 256B = 16 uint4; lane r takes chunks r and r+8
        // (each wave load instruction covers contiguous 128B per group)
        const uint4* tp = reinterpret_cast<const uint4*>(iembH + ((size_t)tw << 7));
        const uint4 t0 = tp[r], t1 = tp[r + 8];

        const uint4* cp = reinterpret_cast<const uint4*>(oembH + ((size_t)cw << 7));
        const uint4 c0 = cp[r], c1 = cp[r + 8];

        float dp = dot16h(t0, t1, c0, c1);

        float dn[NEG];
        #pragma unroll
        for (int j = 0; j < NEG; ++j) {
            const int nw = negw[e * NEG + j];
            const uint4* np_ = reinterpret_cast<const uint4*>(oembH + ((size_t)nw << 7));
            const uint4 n0 = np_[r], n1 = np_[r + 8];
            dn[j] = dot16h(t0, t1, n0, n1);
        }

        // butterfly over the 8-lane group
        #pragma unroll
        for (int m = 4; m >= 1; m >>= 1) {
            dp += __shfl_xor(dp, m, 64);
            #pragma unroll
            for (int j = 0; j < NEG; ++j) dn[j] += __shfl_xor(dn[j], m, 64);
        }

        // all 8 lanes accumulate (8x redundancy divided out in finalize)
        pos_acc += softplus_fast(-dp);             // -log_sigmoid(+dp)
        float s = 0.0f;
        #pragma unroll
        for (int j = 0; j < NEG; ++j) s += softplus_fast(dn[j]);  // -log_sigmoid(-dn)
        neg_acc += s;
    }

    // full-wave butterfly, one atomic pair per wave
    #pragma unroll
    for (int m = 32; m >= 1; m >>= 1) {
        pos_acc += __shfl_xor(pos_acc, m, 64);
        neg_acc += __shfl_xor(neg_acc, m, 64);
    }
    if ((tid & 63) == 0) {
        atomicAdd(&acc[0], pos_acc);
        atomicAdd(&acc[1], neg_acc);
    }
}

__global__ void ns_finalize_h_kernel(const float* __restrict__ acc, float* __restrict__ out) {
    out[0] = acc[0] * (1.0f / ((float)BATCH * 8.0f));
    out[1] = acc[1] * (1.0f / ((float)BATCH * (float)NEG * 8.0f));
}

// ================= fp32 fallback (round-4 kernel, unchanged) =================
__global__ __launch_bounds__(256) void ns_loss_f32_kernel(
    const int* __restrict__ tgt, const int* __restrict__ ctx,
    const int* __restrict__ negw,
    const float* __restrict__ iemb, const float* __restrict__ oemb,
    float* __restrict__ acc)
{
    const int tid = threadIdx.x;
    const int r   = tid & 7;
    const int grp = tid >> 3;
    const int e0  = blockIdx.x * 32 + grp;
    const int estride = gridDim.x * 32;

    float pos_acc = 0.0f, neg_acc = 0.0f;
    for (int e = e0; e < BATCH; e += estride) {
        const int tw = tgt[e];
        const int cw = ctx[e];
        const float4* tp = reinterpret_cast<const float4*>(iemb + (size_t)tw * DIM) + r * 4;
        const float4 t0 = tp[0], t1 = tp[1], t2 = tp[2], t3 = tp[3];
        const float4* cp = reinterpret_cast<const float4*>(oemb + (size_t)cw * DIM) + r * 4;
        float dp = t0.x*cp[0].x+t0.y*cp[0].y+t0.z*cp[0].z+t0.w*cp[0].w
                 + t1.x*cp[1].x+t1.y*cp[1].y+t1.z*cp[1].z+t1.w*cp[1].w
                 + t2.x*cp[2].x+t2.y*cp[2].y+t2.z*cp[2].z+t2.w*cp[2].w
                 + t3.x*cp[3].x+t3.y*cp[3].y+t3.z*cp[3].z+t3.w*cp[3].w;
        float dn[NEG];
        #pragma unroll
        for (int j = 0; j < NEG; ++j) {
            const int nw = negw[e * NEG + j];
            const float4* np_ = reinterpret_cast<const float4*>(oemb + (size_t)nw * DIM) + r * 4;
            dn[j] = t0.x*np_[0].x+t0.y*np_[0].y+t0.z*np_[0].z+t0.w*np_[0].w
                  + t1.x*np_[1].x+t1.y*np_[1].y+t1.z*np_[1].z+t1.w*np_[1].w
                  + t2.x*np_[2].x+t2.y*np_[2].y+t2.z*np_[2].z+t2.w*np_[2].w
                  + t3.x*np_[3].x+t3.y*np_[3].y+t3.z*np_[3].z+t3.w*np_[3].w;
        }
        #pragma unroll
        for (int m = 4; m >= 1; m >>= 1) {
            dp += __shfl_xor(dp, m, 64);
            #pragma unroll
            for (int j = 0; j < NEG; ++j) dn[j] += __shfl_xor(dn[j], m, 64);
        }
        pos_acc += softplus_fast(-dp);
        float s = 0.0f;
        #pragma unroll
        for (int j = 0; j < NEG; ++j) s += softplus_fast(dn[j]);
        neg_acc += s;
    }
    #pragma unroll
    for (int m = 32; m >= 1; m >>= 1) {
        pos_acc += __shfl_xor(pos_acc, m, 64);
        neg_acc += __shfl_xor(neg_acc, m, 64);
    }
    if ((tid & 63) == 0) {
        atomicAdd(&acc[0], pos_acc);
        atomicAdd(&acc[1], neg_acc);
    }
}

__global__ void ns_finalize_f32_kernel(const float* __restrict__ acc, float* __restrict__ out) {
    out[0] = acc[0] * (1.0f / ((float)BATCH * 8.0f));
    out[1] = acc[1] * (1.0f / ((float)BATCH * (float)NEG * 8.0f));
}

extern "C" void kernel_launch(void* const* d_in, const int* in_sizes, int n_in,
                              void* d_out, int out_size, void* d_ws, size_t ws_size,
                              hipStream_t stream) {
    const int*   tgt  = (const int*)d_in[0];
    const int*   ctx  = (const int*)d_in[1];
    const int*   negw = (const int*)d_in[2];
    const float* iemb = (const float*)d_in[3];
    const float* oemb = (const float*)d_in[4];
    float* out = (float*)d_out;
    float* acc = (float*)d_ws;

    if (ws_size >= WS_NEEDED) {
        f16* iembH = (f16*)((char*)d_ws + 256);
        f16* oembH = (f16*)((char*)d_ws + 256 + TABLE_HALF_BYTES);
        ns_init_kernel<<<1, 1, 0, stream>>>(acc);
        ns_convert_kernel<<<2048, 256, 0, stream>>>(iemb, oemb, iembH, oembH);
        ns_loss_h_kernel<<<NBLOCK, NTHREADS, 0, stream>>>(tgt, ctx, negw, iembH, oembH, acc);
        ns_finalize_h_kernel<<<1, 1, 0, stream>>>(acc, out);
    } else {
        ns_init_kernel<<<1, 1, 0, stream>>>(acc);
        ns_loss_f32_kernel<<<2048, 256, 0, stream>>>(tgt, ctx, negw, iemb, oemb, acc);
        ns_finalize_f32_kernel<<<1, 1, 0, stream>>>(acc, out);
    }
}

// Round 8
// 264.262 us; speedup vs baseline: 1.0512x; 1.0512x over previous
//
#include <hip/hip_runtime.h>

typedef _Float16 f16;
typedef _Float16 f16x2 __attribute__((ext_vector_type(2)));
typedef _Float16 f16x4 __attribute__((ext_vector_type(4)));

#define VOCAB 100000
#define DIM 128
#define BATCH 262144
#define NEG 5

#define NBLOCK 2048
#define NTHREADS 256
#define NGROUPS (NBLOCK * NTHREADS / 16)   // 32768 16-lane groups
#define EPG (BATCH / NGROUPS)              // 8 elements per group, exact

#define TABLE_HALF_BYTES ((size_t)VOCAB * DIM * 2)            // 25.6 MB
#define WS_NEEDED (256 + 2 * TABLE_HALF_BYTES)

// log(1 + exp(x)); |x| <~ 0.04 here so exp(-|x|) ~ 1: no cancellation risk.
__device__ __forceinline__ float softplus_fast(float x) {
    return fmaxf(x, 0.0f) + __logf(1.0f + __expf(-fabsf(x)));
}

__device__ __forceinline__ float fdot2h(f16x2 a, f16x2 b, float c) {
#if __has_builtin(__builtin_amdgcn_fdot2)
    return __builtin_amdgcn_fdot2(a, b, c, false);
#else
    return c + (float)a[0] * (float)b[0] + (float)a[1] * (float)b[1];
#endif
}

// dot of 8 halves (one dwordx4 each side), fp32 accumulate, 2 chains
__device__ __forceinline__ float dot8h(uint4 a, uint4 b) {
    union { uint4 u; f16x2 h[4]; } A, B;
    A.u = a; B.u = b;
    float s0 = fdot2h(A.h[0], B.h[0], 0.0f);
    float s1 = fdot2h(A.h[1], B.h[1], 0.0f);
    s0 = fdot2h(A.h[2], B.h[2], s0);
    s1 = fdot2h(A.h[3], B.h[3], s1);
    return s0 + s1;
}

__global__ void ns_init_kernel(float* acc) {
    acc[0] = 0.0f;
    acc[1] = 0.0f;
}

// ---- streaming fp32 -> fp16 conversion of both tables ----
__global__ __launch_bounds__(256) void ns_convert_kernel(
    const float* __restrict__ iemb, const float* __restrict__ oemb,
    f16* __restrict__ iembH, f16* __restrict__ oembH)
{
    const int n4 = VOCAB * DIM / 4;
    int i = blockIdx.x * blockDim.x + threadIdx.x;
    const int stride = gridDim.x * blockDim.x;
    for (; i < n4; i += stride) {
        float4 a = reinterpret_cast<const float4*>(iemb)[i];
        f16x4 ha = {(f16)a.x, (f16)a.y, (f16)a.z, (f16)a.w};
        reinterpret_cast<f16x4*>(iembH)[i] = ha;
        float4 b = reinterpret_cast<const float4*>(oemb)[i];
        f16x4 hb = {(f16)b.x, (f16)b.y, (f16)b.z, (f16)b.w};
        reinterpret_cast<f16x4*>(oembH)[i] = hb;
    }
}

// ---- fp16 gather loss: 16 lanes/element, 2-deep named-register pipeline ----
__global__ __launch_bounds__(NTHREADS) void ns_loss_h_kernel(
    const int* __restrict__ tgt,
    const int* __restrict__ ctx,
    const int* __restrict__ negw,
    const f16* __restrict__ iembH,
    const f16* __restrict__ oembH,
    float* __restrict__ acc)
{
    const int tid    = threadIdx.x;
    const int l      = tid & 15;                                  // 16B chunk in 256B row
    const int group0 = (blockIdx.x * NTHREADS + tid) >> 4;        // global group id

    float pos = 0.0f, neg = 0.0f;

    // named registers: two sets of {7 indices, 7 row fragments}
    int ia0, ia1, ia2, ia3, ia4, ia5, ia6;
    int ib0, ib1, ib2, ib3, ib4, ib5, ib6;
    uint4 tA, cA, nA0, nA1, nA2, nA3, nA4;
    uint4 tB, cB, nB0, nB1, nB2, nB3, nB4;

    #define LOAD_IDX(it, i0, i1, i2, i3, i4, i5, i6) do {               \
        const int e_ = group0 + (it) * NGROUPS;                         \
        i0 = tgt[e_];                                                   \
        i1 = ctx[e_];                                                   \
        const int* nb_ = negw + (size_t)e_ * NEG;                       \
        i2 = nb_[0]; i3 = nb_[1]; i4 = nb_[2]; i5 = nb_[3]; i6 = nb_[4];\
    } while (0)

    #define LOAD_ROWS(i0, i1, i2, i3, i4, i5, i6, t_, c_, n0_, n1_, n2_, n3_, n4_) do { \
        const char* ib_ = (const char*)iembH;                                           \
        const char* ob_ = (const char*)oembH;                                           \
        const int  lo_ = l << 4;                                                        \
        t_  = *(const uint4*)(ib_ + (((size_t)(i0)) << 8) + lo_);                       \
        c_  = *(const uint4*)(ob_ + (((size_t)(i1)) << 8) + lo_);                       \
        n0_ = *(const uint4*)(ob_ + (((size_t)(i2)) << 8) + lo_);                       \
        n1_ = *(const uint4*)(ob_ + (((size_t)(i3)) << 8) + lo_);                       \
        n2_ = *(const uint4*)(ob_ + (((size_t)(i4)) << 8) + lo_);                       \
        n3_ = *(const uint4*)(ob_ + (((size_t)(i5)) << 8) + lo_);                       \
        n4_ = *(const uint4*)(ob_ + (((size_t)(i6)) << 8) + lo_);                       \
    } while (0)

    #define COMPUTE(t_, c_, n0_, n1_, n2_, n3_, n4_) do {               \
        float dp = dot8h(t_, c_);                                       \
        float d0 = dot8h(t_, n0_);                                      \
        float d1 = dot8h(t_, n1_);                                      \
        float d2 = dot8h(t_, n2_);                                      \
        float d3 = dot8h(t_, n3_);                                      \
        float d4 = dot8h(t_, n4_);                                      \
        _Pragma("unroll")                                               \
        for (int m_ = 8; m_ >= 1; m_ >>= 1) {                           \
            dp += __shfl_xor(dp, m_, 64);                               \
            d0 += __shfl_xor(d0, m_, 64);                               \
            d1 += __shfl_xor(d1, m_, 64);                               \
            d2 += __shfl_xor(d2, m_, 64);                               \
            d3 += __shfl_xor(d3, m_, 64);                               \
            d4 += __shfl_xor(d4, m_, 64);                               \
        }                                                               \
        pos += softplus_fast(-dp);                                      \
        neg += softplus_fast(d0) + softplus_fast(d1) + softplus_fast(d2)\
             + softplus_fast(d3) + softplus_fast(d4);                   \
    } while (0)

    // prologue: idx(0) -> A; rows(0) -> A; idx(1) -> B
    LOAD_IDX(0, ia0, ia1, ia2, ia3, ia4, ia5, ia6);
    LOAD_ROWS(ia0, ia1, ia2, ia3, ia4, ia5, ia6, tA, cA, nA0, nA1, nA2, nA3, nA4);
    LOAD_IDX(1, ib0, ib1, ib2, ib3, ib4, ib5, ib6);
    __builtin_amdgcn_sched_barrier(0);

    // steady state, fully unrolled. Per iteration (program order):
    //   [IDX(it+2)]  [ROWS(it+1)]  [COMPUTE(it)]
    // IDX-first means waiting on indices never drains the newest row loads
    // (vmcnt is in-order), so >=7 row loads stay in flight across compute.
    #pragma unroll
    for (int it = 0; it < EPG; ++it) {
        if ((it & 1) == 0) {
            if (it + 2 < EPG) LOAD_IDX(it + 2, ia0, ia1, ia2, ia3, ia4, ia5, ia6);
            __builtin_amdgcn_sched_barrier(0);
            if (it + 1 < EPG) LOAD_ROWS(ib0, ib1, ib2, ib3, ib4, ib5, ib6,
                                        tB, cB, nB0, nB1, nB2, nB3, nB4);
            __builtin_amdgcn_sched_barrier(0);
            COMPUTE(tA, cA, nA0, nA1, nA2, nA3, nA4);
            __builtin_amdgcn_sched_barrier(0);
        } else {
            if (it + 2 < EPG) LOAD_IDX(it + 2, ib0, ib1, ib2, ib3, ib4, ib5, ib6);
            __builtin_amdgcn_sched_barrier(0);
            if (it + 1 < EPG) LOAD_ROWS(ia0, ia1, ia2, ia3, ia4, ia5, ia6,
                                        tA, cA, nA0, nA1, nA2, nA3, nA4);
            __builtin_amdgcn_sched_barrier(0);
            COMPUTE(tB, cB, nB0, nB1, nB2, nB3, nB4);
            __builtin_amdgcn_sched_barrier(0);
        }
    }

    #undef LOAD_IDX
    #undef LOAD_ROWS
    #undef COMPUTE

    // full-wave butterfly, one atomic pair per wave
    #pragma unroll
    for (int m = 32; m >= 1; m >>= 1) {
        pos += __shfl_xor(pos, m, 64);
        neg += __shfl_xor(neg, m, 64);
    }
    if ((tid & 63) == 0) {
        atomicAdd(&acc[0], pos);
        atomicAdd(&acc[1], neg);
    }
}

__global__ void ns_finalize_h_kernel(const float* __restrict__ acc, float* __restrict__ out) {
    // each element accumulated by its 16 lanes
    out[0] = acc[0] * (1.0f / ((float)BATCH * 16.0f));
    out[1] = acc[1] * (1.0f / ((float)BATCH * (float)NEG * 16.0f));
}

// ================= fp32 fallback (round-4 kernel, unchanged) =================
__device__ __forceinline__ float dot4f(float4 a, float4 b) {
    return a.x * b.x + a.y * b.y + a.z * b.z + a.w * b.w;
}

__global__ __launch_bounds__(256) void ns_loss_f32_kernel(
    const int* __restrict__ tgt, const int* __restrict__ ctx,
    const int* __restrict__ negw,
    const float* __restrict__ iemb, const float* __restrict__ oemb,
    float* __restrict__ acc)
{
    const int tid = threadIdx.x;
    const int r   = tid & 7;
    const int grp = tid >> 3;
    const int e0  = blockIdx.x * 32 + grp;
    const int estride = gridDim.x * 32;

    float pos_acc = 0.0f, neg_acc = 0.0f;
    for (int e = e0; e < BATCH; e += estride) {
        const int tw = tgt[e];
        const int cw = ctx[e];
        const float4* tp = reinterpret_cast<const float4*>(iemb + (size_t)tw * DIM) + r * 4;
        const float4 t0 = tp[0], t1 = tp[1], t2 = tp[2], t3 = tp[3];
        const float4* cp = reinterpret_cast<const float4*>(oemb + (size_t)cw * DIM) + r * 4;
        float dp = dot4f(t0, cp[0]) + dot4f(t1, cp[1]) + dot4f(t2, cp[2]) + dot4f(t3, cp[3]);
        float dn[NEG];
        #pragma unroll
        for (int j = 0; j < NEG; ++j) {
            const int nw = negw[e * NEG + j];
            const float4* np_ = reinterpret_cast<const float4*>(oemb + (size_t)nw * DIM) + r * 4;
            dn[j] = dot4f(t0, np_[0]) + dot4f(t1, np_[1]) + dot4f(t2, np_[2]) + dot4f(t3, np_[3]);
        }
        #pragma unroll
        for (int m = 4; m >= 1; m >>= 1) {
            dp += __shfl_xor(dp, m, 64);
            #pragma unroll
            for (int j = 0; j < NEG; ++j) dn[j] += __shfl_xor(dn[j], m, 64);
        }
        pos_acc += softplus_fast(-dp);
        float s = 0.0f;
        #pragma unroll
        for (int j = 0; j < NEG; ++j) s += softplus_fast(dn[j]);
        neg_acc += s;
    }
    #pragma unroll
    for (int m = 32; m >= 1; m >>= 1) {
        pos_acc += __shfl_xor(pos_acc, m, 64);
        neg_acc += __shfl_xor(neg_acc, m, 64);
    }
    if ((tid & 63) == 0) {
        atomicAdd(&acc[0], pos_acc);
        atomicAdd(&acc[1], neg_acc);
    }
}

__global__ void ns_finalize_f32_kernel(const float* __restrict__ acc, float* __restrict__ out) {
    out[0] = acc[0] * (1.0f / ((float)BATCH * 8.0f));
    out[1] = acc[1] * (1.0f / ((float)BATCH * (float)NEG * 8.0f));
}

extern "C" void kernel_launch(void* const* d_in, const int* in_sizes, int n_in,
                              void* d_out, int out_size, void* d_ws, size_t ws_size,
                              hipStream_t stream) {
    const int*   tgt  = (const int*)d_in[0];
    const int*   ctx  = (const int*)d_in[1];
    const int*   negw = (const int*)d_in[2];
    const float* iemb = (const float*)d_in[3];
    const float* oemb = (const float*)d_in[4];
    float* out = (float*)d_out;
    float* acc = (float*)d_ws;

    if (ws_size >= WS_NEEDED) {
        f16* iembH = (f16*)((char*)d_ws + 256);
        f16* oembH = (f16*)((char*)d_ws + 256 + TABLE_HALF_BYTES);
        ns_init_kernel<<<1, 1, 0, stream>>>(acc);
        ns_convert_kernel<<<2048, 256, 0, stream>>>(iemb, oemb, iembH, oembH);
        ns_loss_h_kernel<<<NBLOCK, NTHREADS, 0, stream>>>(tgt, ctx, negw, iembH, oembH, acc);
        ns_finalize_h_kernel<<<1, 1, 0, stream>>>(acc, out);
    } else {
        ns_init_kernel<<<1, 1, 0, stream>>>(acc);
        ns_loss_f32_kernel<<<2048, 256, 0, stream>>>(tgt, ctx, negw, iemb, oemb, acc);
        ns_finalize_f32_kernel<<<1, 1, 0, stream>>>(acc, out);
    }
}

// Round 9
// 261.346 us; speedup vs baseline: 1.0629x; 1.0112x over previous
//
#include <hip/hip_runtime.h>

typedef _Float16 f16;
typedef _Float16 f16x2 __attribute__((ext_vector_type(2)));
typedef _Float16 f16x4 __attribute__((ext_vector_type(4)));

#define VOCAB 100000
#define DIM 128
#define BATCH 262144
#define NEG 5

#define NBLOCK 2048
#define NTHREADS 256
#define NGROUPS (NBLOCK * NTHREADS / 16)   // 32768 16-lane groups
#define EPG (BATCH / NGROUPS)              // 8 elements per group, exact

#define TABLE_HALF_BYTES ((size_t)VOCAB * DIM * 2)            // 25.6 MB
#define WS_NEEDED (256 + 2 * TABLE_HALF_BYTES)

// log(1 + exp(x)); |x| <~ 0.04 here so exp(-|x|) ~ 1: no cancellation risk.
__device__ __forceinline__ float softplus_fast(float x) {
    return fmaxf(x, 0.0f) + __logf(1.0f + __expf(-fabsf(x)));
}

__device__ __forceinline__ float fdot2h(f16x2 a, f16x2 b, float c) {
#if __has_builtin(__builtin_amdgcn_fdot2)
    return __builtin_amdgcn_fdot2(a, b, c, false);
#else
    return c + (float)a[0] * (float)b[0] + (float)a[1] * (float)b[1];
#endif
}

// dot of 8 halves (one dwordx4 each side), fp32 accumulate, 2 chains
__device__ __forceinline__ float dot8h(uint4 a, uint4 b) {
    union { uint4 u; f16x2 h[4]; } A, B;
    A.u = a; B.u = b;
    float s0 = fdot2h(A.h[0], B.h[0], 0.0f);
    float s1 = fdot2h(A.h[1], B.h[1], 0.0f);
    s0 = fdot2h(A.h[2], B.h[2], s0);
    s1 = fdot2h(A.h[3], B.h[3], s1);
    return s0 + s1;
}

__global__ void ns_init_kernel(float* acc) {
    acc[0] = 0.0f;
    acc[1] = 0.0f;
}

// ---- streaming fp32 -> fp16 conversion of both tables ----
__global__ __launch_bounds__(256) void ns_convert_kernel(
    const float* __restrict__ iemb, const float* __restrict__ oemb,
    f16* __restrict__ iembH, f16* __restrict__ oembH)
{
    const int n4 = VOCAB * DIM / 4;
    int i = blockIdx.x * blockDim.x + threadIdx.x;
    const int stride = gridDim.x * blockDim.x;
    for (; i < n4; i += stride) {
        float4 a = reinterpret_cast<const float4*>(iemb)[i];
        f16x4 ha = {(f16)a.x, (f16)a.y, (f16)a.z, (f16)a.w};
        reinterpret_cast<f16x4*>(iembH)[i] = ha;
        float4 b = reinterpret_cast<const float4*>(oemb)[i];
        f16x4 hb = {(f16)b.x, (f16)b.y, (f16)b.z, (f16)b.w};
        reinterpret_cast<f16x4*>(oembH)[i] = hb;
    }
}

// ---- fp16 gather loss: 16 lanes/element, 2-deep named-register pipeline ----
// __launch_bounds__(256, 4): 4 waves/SIMD min -> 128-VGPR budget. This is the
// critical knob: at the default (8 waves/SIMD, 64-VGPR cap) the allocator
// sinks every row load next to its use and the pipeline serializes.
__global__ __launch_bounds__(NTHREADS, 4) void ns_loss_h_kernel(
    const int* __restrict__ tgt,
    const int* __restrict__ ctx,
    const int* __restrict__ negw,
    const f16* __restrict__ iembH,
    const f16* __restrict__ oembH,
    float* __restrict__ acc)
{
    const int tid    = threadIdx.x;
    const int l      = tid & 15;                                  // 16B chunk in 256B row
    const int group0 = (blockIdx.x * NTHREADS + tid) >> 4;        // global group id

    float pos = 0.0f, neg = 0.0f;

    // named registers: two sets of {7 indices, 7 row fragments}
    int ia0, ia1, ia2, ia3, ia4, ia5, ia6;
    int ib0, ib1, ib2, ib3, ib4, ib5, ib6;
    uint4 tA, cA, nA0, nA1, nA2, nA3, nA4;
    uint4 tB, cB, nB0, nB1, nB2, nB3, nB4;

    #define LOAD_IDX(it, i0, i1, i2, i3, i4, i5, i6) do {               \
        const int e_ = group0 + (it) * NGROUPS;                         \
        i0 = tgt[e_];                                                   \
        i1 = ctx[e_];                                                   \
        const int* nb_ = negw + (size_t)e_ * NEG;                       \
        i2 = nb_[0]; i3 = nb_[1]; i4 = nb_[2]; i5 = nb_[3]; i6 = nb_[4];\
    } while (0)

    #define LOAD_ROWS(i0, i1, i2, i3, i4, i5, i6, t_, c_, n0_, n1_, n2_, n3_, n4_) do { \
        const char* ib_ = (const char*)iembH;                                           \
        const char* ob_ = (const char*)oembH;                                           \
        const int  lo_ = l << 4;                                                        \
        t_  = *(const uint4*)(ib_ + (((size_t)(i0)) << 8) + lo_);                       \
        c_  = *(const uint4*)(ob_ + (((size_t)(i1)) << 8) + lo_);                       \
        n0_ = *(const uint4*)(ob_ + (((size_t)(i2)) << 8) + lo_);                       \
        n1_ = *(const uint4*)(ob_ + (((size_t)(i3)) << 8) + lo_);                       \
        n2_ = *(const uint4*)(ob_ + (((size_t)(i4)) << 8) + lo_);                       \
        n3_ = *(const uint4*)(ob_ + (((size_t)(i5)) << 8) + lo_);                       \
        n4_ = *(const uint4*)(ob_ + (((size_t)(i6)) << 8) + lo_);                       \
    } while (0)

    #define COMPUTE(t_, c_, n0_, n1_, n2_, n3_, n4_) do {               \
        float dp = dot8h(t_, c_);                                       \
        float d0 = dot8h(t_, n0_);                                      \
        float d1 = dot8h(t_, n1_);                                      \
        float d2 = dot8h(t_, n2_);                                      \
        float d3 = dot8h(t_, n3_);                                      \
        float d4 = dot8h(t_, n4_);                                      \
        _Pragma("unroll")                                               \
        for (int m_ = 8; m_ >= 1; m_ >>= 1) {                           \
            dp += __shfl_xor(dp, m_, 64);                               \
            d0 += __shfl_xor(d0, m_, 64);                               \
            d1 += __shfl_xor(d1, m_, 64);                               \
            d2 += __shfl_xor(d2, m_, 64);                               \
            d3 += __shfl_xor(d3, m_, 64);                               \
            d4 += __shfl_xor(d4, m_, 64);                               \
        }                                                               \
        pos += softplus_fast(-dp);                                      \
        neg += softplus_fast(d0) + softplus_fast(d1) + softplus_fast(d2)\
             + softplus_fast(d3) + softplus_fast(d4);                   \
    } while (0)

    // prologue: idx(0) -> A; rows(0) -> A; idx(1) -> B
    LOAD_IDX(0, ia0, ia1, ia2, ia3, ia4, ia5, ia6);
    LOAD_ROWS(ia0, ia1, ia2, ia3, ia4, ia5, ia6, tA, cA, nA0, nA1, nA2, nA3, nA4);
    LOAD_IDX(1, ib0, ib1, ib2, ib3, ib4, ib5, ib6);
    __builtin_amdgcn_sched_barrier(0);

    // steady state, fully unrolled. Per iteration (program order):
    //   [IDX(it+2)]  [ROWS(it+1)]  [COMPUTE(it)]
    // IDX-first means waiting on indices never drains the newest row loads
    // (vmcnt is in-order), so >=7 row loads stay in flight across compute.
    #pragma unroll
    for (int it = 0; it < EPG; ++it) {
        if ((it & 1) == 0) {
            if (it + 2 < EPG) LOAD_IDX(it + 2, ia0, ia1, ia2, ia3, ia4, ia5, ia6);
            __builtin_amdgcn_sched_barrier(0);
            if (it + 1 < EPG) LOAD_ROWS(ib0, ib1, ib2, ib3, ib4, ib5, ib6,
                                        tB, cB, nB0, nB1, nB2, nB3, nB4);
            __builtin_amdgcn_sched_barrier(0);
            COMPUTE(tA, cA, nA0, nA1, nA2, nA3, nA4);
            __builtin_amdgcn_sched_barrier(0);
        } else {
            if (it + 2 < EPG) LOAD_IDX(it + 2, ib0, ib1, ib2, ib3, ib4, ib5, ib6);
            __builtin_amdgcn_sched_barrier(0);
            if (it + 1 < EPG) LOAD_ROWS(ia0, ia1, ia2, ia3, ia4, ia5, ia6,
                                        tA, cA, nA0, nA1, nA2, nA3, nA4);
            __builtin_amdgcn_sched_barrier(0);
            COMPUTE(tB, cB, nB0, nB1, nB2, nB3, nB4);
            __builtin_amdgcn_sched_barrier(0);
        }
    }

    #undef LOAD_IDX
    #undef LOAD_ROWS
    #undef COMPUTE

    // full-wave butterfly, one atomic pair per wave
    #pragma unroll
    for (int m = 32; m >= 1; m >>= 1) {
        pos += __shfl_xor(pos, m, 64);
        neg += __shfl_xor(neg, m, 64);
    }
    if ((tid & 63) == 0) {
        atomicAdd(&acc[0], pos);
        atomicAdd(&acc[1], neg);
    }
}

__global__ void ns_finalize_h_kernel(const float* __restrict__ acc, float* __restrict__ out) {
    // each element accumulated by its 16 lanes
    out[0] = acc[0] * (1.0f / ((float)BATCH * 16.0f));
    out[1] = acc[1] * (1.0f / ((float)BATCH * (float)NEG * 16.0f));
}

// ================= fp32 fallback (round-4 kernel, unchanged) =================
__device__ __forceinline__ float dot4f(float4 a, float4 b) {
    return a.x * b.x + a.y * b.y + a.z * b.z + a.w * b.w;
}

__global__ __launch_bounds__(256) void ns_loss_f32_kernel(
    const int* __restrict__ tgt, const int* __restrict__ ctx,
    const int* __restrict__ negw,
    const float* __restrict__ iemb, const float* __restrict__ oemb,
    float* __restrict__ acc)
{
    const int tid = threadIdx.x;
    const int r   = tid & 7;
    const int grp = tid >> 3;
    const int e0  = blockIdx.x * 32 + grp;
    const int estride = gridDim.x * 32;

    float pos_acc = 0.0f, neg_acc = 0.0f;
    for (int e = e0; e < BATCH; e += estride) {
        const int tw = tgt[e];
        const int cw = ctx[e];
        const float4* tp = reinterpret_cast<const float4*>(iemb + (size_t)tw * DIM) + r * 4;
        const float4 t0 = tp[0], t1 = tp[1], t2 = tp[2], t3 = tp[3];
        const float4* cp = reinterpret_cast<const float4*>(oemb + (size_t)cw * DIM) + r * 4;
        float dp = dot4f(t0, cp[0]) + dot4f(t1, cp[1]) + dot4f(t2, cp[2]) + dot4f(t3, cp[3]);
        float dn[NEG];
        #pragma unroll
        for (int j = 0; j < NEG; ++j) {
            const int nw = negw[e * NEG + j];
            const float4* np_ = reinterpret_cast<const float4*>(oemb + (size_t)nw * DIM) + r * 4;
            dn[j] = dot4f(t0, np_[0]) + dot4f(t1, np_[1]) + dot4f(t2, np_[2]) + dot4f(t3, np_[3]);
        }
        #pragma unroll
        for (int m = 4; m >= 1; m >>= 1) {
            dp += __shfl_xor(dp, m, 64);
            #pragma unroll
            for (int j = 0; j < NEG; ++j) dn[j] += __shfl_xor(dn[j], m, 64);
        }
        pos_acc += softplus_fast(-dp);
        float s = 0.0f;
        #pragma unroll
        for (int j = 0; j < NEG; ++j) s += softplus_fast(dn[j]);
        neg_acc += s;
    }
    #pragma unroll
    for (int m = 32; m >= 1; m >>= 1) {
        pos_acc += __shfl_xor(pos_acc, m, 64);
        neg_acc += __shfl_xor(neg_acc, m, 64);
    }
    if ((tid & 63) == 0) {
        atomicAdd(&acc[0], pos_acc);
        atomicAdd(&acc[1], neg_acc);
    }
}

__global__ void ns_finalize_f32_kernel(const float* __restrict__ acc, float* __restrict__ out) {
    out[0] = acc[0] * (1.0f / ((float)BATCH * 8.0f));
    out[1] = acc[1] * (1.0f / ((float)BATCH * (float)NEG * 8.0f));
}

extern "C" void kernel_launch(void* const* d_in, const int* in_sizes, int n_in,
                              void* d_out, int out_size, void* d_ws, size_t ws_size,
                              hipStream_t stream) {
    const int*   tgt  = (const int*)d_in[0];
    const int*   ctx  = (const int*)d_in[1];
    const int*   negw = (const int*)d_in[2];
    const float* iemb = (const float*)d_in[3];
    const float* oemb = (const float*)d_in[4];
    float* out = (float*)d_out;
    float* acc = (float*)d_ws;

    if (ws_size >= WS_NEEDED) {
        f16* iembH = (f16*)((char*)d_ws + 256);
        f16* oembH = (f16*)((char*)d_ws + 256 + TABLE_HALF_BYTES);
        ns_init_kernel<<<1, 1, 0, stream>>>(acc);
        ns_convert_kernel<<<2048, 256, 0, stream>>>(iemb, oemb, iembH, oembH);
        ns_loss_h_kernel<<<NBLOCK, NTHREADS, 0, stream>>>(tgt, ctx, negw, iembH, oembH, acc);
        ns_finalize_h_kernel<<<1, 1, 0, stream>>>(acc, out);
    } else {
        ns_init_kernel<<<1, 1, 0, stream>>>(acc);
        ns_loss_f32_kernel<<<2048, 256, 0, stream>>>(tgt, ctx, negw, iemb, oemb, acc);
        ns_finalize_f32_kernel<<<1, 1, 0, stream>>>(acc, out);
    }
}

// Round 10
// 259.783 us; speedup vs baseline: 1.0693x; 1.0060x over previous
//
#include <hip/hip_runtime.h>

typedef _Float16 f16;
typedef _Float16 f16x2 __attribute__((ext_vector_type(2)));
typedef _Float16 f16x4 __attribute__((ext_vector_type(4)));

#define VOCAB 100000
#define DIM 128
#define BATCH 262144
#define NEG 5

#define NBLOCK 2048
#define NTHREADS 256
#define NGROUPS (NBLOCK * NTHREADS / 16)   // 32768 16-lane groups
#define EPG (BATCH / NGROUPS)              // 8 elements per group, exact
#define MEGA 4                             // elements batched per issue wave
#define NMEGA (EPG / MEGA)                 // 2 mega-batches per group

#define TABLE_HALF_BYTES ((size_t)VOCAB * DIM * 2)            // 25.6 MB
#define WS_NEEDED (256 + 2 * TABLE_HALF_BYTES)

// log(1 + exp(x)); |x| <~ 0.04 here so exp(-|x|) ~ 1: no cancellation risk.
__device__ __forceinline__ float softplus_fast(float x) {
    return fmaxf(x, 0.0f) + __logf(1.0f + __expf(-fabsf(x)));
}

__device__ __forceinline__ float fdot2h(f16x2 a, f16x2 b, float c) {
#if __has_builtin(__builtin_amdgcn_fdot2)
    return __builtin_amdgcn_fdot2(a, b, c, false);
#else
    return c + (float)a[0] * (float)b[0] + (float)a[1] * (float)b[1];
#endif
}

// dot of 8 halves (one dwordx4 each side), fp32 accumulate, 2 chains
__device__ __forceinline__ float dot8h(uint4 a, uint4 b) {
    union { uint4 u; f16x2 h[4]; } A, B;
    A.u = a; B.u = b;
    float s0 = fdot2h(A.h[0], B.h[0], 0.0f);
    float s1 = fdot2h(A.h[1], B.h[1], 0.0f);
    s0 = fdot2h(A.h[2], B.h[2], s0);
    s1 = fdot2h(A.h[3], B.h[3], s1);
    return s0 + s1;
}

__global__ void ns_init_kernel(float* acc) {
    acc[0] = 0.0f;
    acc[1] = 0.0f;
}

// ---- streaming fp32 -> fp16 conversion of both tables ----
__global__ __launch_bounds__(256) void ns_convert_kernel(
    const float* __restrict__ iemb, const float* __restrict__ oemb,
    f16* __restrict__ iembH, f16* __restrict__ oembH)
{
    const int n4 = VOCAB * DIM / 4;
    int i = blockIdx.x * blockDim.x + threadIdx.x;
    const int stride = gridDim.x * blockDim.x;
    for (; i < n4; i += stride) {
        float4 a = reinterpret_cast<const float4*>(iemb)[i];
        f16x4 ha = {(f16)a.x, (f16)a.y, (f16)a.z, (f16)a.w};
        reinterpret_cast<f16x4*>(iembH)[i] = ha;
        float4 b = reinterpret_cast<const float4*>(oemb)[i];
        f16x4 hb = {(f16)b.x, (f16)b.y, (f16)b.z, (f16)b.w};
        reinterpret_cast<f16x4*>(oembH)[i] = hb;
    }
}

// ---- fp16 gather loss: 16 lanes/element, MEGA=4 elements batched per issue.
// Queue-dominated gather regime: per-wave throughput ~ bytes kept in flight.
// 28 x 1KB wave-loads in flight (28 KB/wave) matches R4's winning depth at
// half the bytes. launch_bounds(256,3): ~170-VGPR budget for the 112-VGPR
// row buffer.
__global__ __launch_bounds__(NTHREADS, 3) void ns_loss_h_kernel(
    const int* __restrict__ tgt,
    const int* __restrict__ ctx,
    const int* __restrict__ negw,
    const f16* __restrict__ iembH,
    const f16* __restrict__ oembH,
    float* __restrict__ acc)
{
    const int tid    = threadIdx.x;
    const int l      = tid & 15;                               // 16B chunk in 256B row
    const uint32_t lo = (uint32_t)(l << 4);
    const int group0 = (blockIdx.x * NTHREADS + tid) >> 4;     // global group id

    const char* ib = (const char*)iembH;
    const char* ob = (const char*)oembH;

    float pos = 0.0f, neg = 0.0f;

    #pragma unroll
    for (int m = 0; m < NMEGA; ++m) {
        int   idx[MEGA][7];
        uint4 rows[MEGA][7];

        // ---- issue all 28 index loads (coalesced streams) ----
        #pragma unroll
        for (int k = 0; k < MEGA; ++k) {
            const int e = group0 + (m * MEGA + k) * NGROUPS;
            idx[k][0] = tgt[e];
            idx[k][1] = ctx[e];
            const int* nb = negw + (size_t)e * NEG;
            #pragma unroll
            for (int j = 0; j < NEG; ++j) idx[k][2 + j] = nb[j];
        }
        __builtin_amdgcn_sched_barrier(0);

        // ---- issue all 28 row loads as one batch (28 KB/wave in flight) ----
        #pragma unroll
        for (int k = 0; k < MEGA; ++k) {
            rows[k][0] = *(const uint4*)(ib + ((((uint32_t)idx[k][0]) << 8) + lo));
            #pragma unroll
            for (int q = 1; q < 7; ++q)
                rows[k][q] = *(const uint4*)(ob + ((((uint32_t)idx[k][q]) << 8) + lo));
        }
        __builtin_amdgcn_sched_barrier(0);

        // ---- compute the 4 elements (counted vmcnt: el0 compute overlaps
        //      arrival of el1..3 rows) ----
        #pragma unroll
        for (int k = 0; k < MEGA; ++k) {
            float dp = dot8h(rows[k][0], rows[k][1]);
            float d0 = dot8h(rows[k][0], rows[k][2]);
            float d1 = dot8h(rows[k][0], rows[k][3]);
            float d2 = dot8h(rows[k][0], rows[k][4]);
            float d3 = dot8h(rows[k][0], rows[k][5]);
            float d4 = dot8h(rows[k][0], rows[k][6]);
            #pragma unroll
            for (int s = 8; s >= 1; s >>= 1) {
                dp += __shfl_xor(dp, s, 64);
                d0 += __shfl_xor(d0, s, 64);
                d1 += __shfl_xor(d1, s, 64);
                d2 += __shfl_xor(d2, s, 64);
                d3 += __shfl_xor(d3, s, 64);
                d4 += __shfl_xor(d4, s, 64);
            }
            pos += softplus_fast(-dp);                     // -log_sigmoid(+dp)
            neg += softplus_fast(d0) + softplus_fast(d1) + softplus_fast(d2)
                 + softplus_fast(d3) + softplus_fast(d4);  // -log_sigmoid(-dn)
        }
    }

    // full-wave butterfly, one atomic pair per wave
    #pragma unroll
    for (int s = 32; s >= 1; s >>= 1) {
        pos += __shfl_xor(pos, s, 64);
        neg += __shfl_xor(neg, s, 64);
    }
    if ((tid & 63) == 0) {
        atomicAdd(&acc[0], pos);
        atomicAdd(&acc[1], neg);
    }
}

__global__ void ns_finalize_h_kernel(const float* __restrict__ acc, float* __restrict__ out) {
    // each element accumulated by its 16 lanes
    out[0] = acc[0] * (1.0f / ((float)BATCH * 16.0f));
    out[1] = acc[1] * (1.0f / ((float)BATCH * (float)NEG * 16.0f));
}

// ================= fp32 fallback (round-4 kernel, unchanged) =================
__device__ __forceinline__ float dot4f(float4 a, float4 b) {
    return a.x * b.x + a.y * b.y + a.z * b.z + a.w * b.w;
}

__global__ __launch_bounds__(256) void ns_loss_f32_kernel(
    const int* __restrict__ tgt, const int* __restrict__ ctx,
    const int* __restrict__ negw,
    const float* __restrict__ iemb, const float* __restrict__ oemb,
    float* __restrict__ acc)
{
    const int tid = threadIdx.x;
    const int r   = tid & 7;
    const int grp = tid >> 3;
    const int e0  = blockIdx.x * 32 + grp;
    const int estride = gridDim.x * 32;

    float pos_acc = 0.0f, neg_acc = 0.0f;
    for (int e = e0; e < BATCH; e += estride) {
        const int tw = tgt[e];
        const int cw = ctx[e];
        const float4* tp = reinterpret_cast<const float4*>(iemb + (size_t)tw * DIM) + r * 4;
        const float4 t0 = tp[0], t1 = tp[1], t2 = tp[2], t3 = tp[3];
        const float4* cp = reinterpret_cast<const float4*>(oemb + (size_t)cw * DIM) + r * 4;
        float dp = dot4f(t0, cp[0]) + dot4f(t1, cp[1]) + dot4f(t2, cp[2]) + dot4f(t3, cp[3]);
        float dn[NEG];
        #pragma unroll
        for (int j = 0; j < NEG; ++j) {
            const int nw = negw[e * NEG + j];
            const float4* np_ = reinterpret_cast<const float4*>(oemb + (size_t)nw * DIM) + r * 4;
            dn[j] = dot4f(t0, np_[0]) + dot4f(t1, np_[1]) + dot4f(t2, np_[2]) + dot4f(t3, np_[3]);
        }
        #pragma unroll
        for (int m = 4; m >= 1; m >>= 1) {
            dp += __shfl_xor(dp, m, 64);
            #pragma unroll
            for (int j = 0; j < NEG; ++j) dn[j] += __shfl_xor(dn[j], m, 64);
        }
        pos_acc += softplus_fast(-dp);
        float s = 0.0f;
        #pragma unroll
        for (int j = 0; j < NEG; ++j) s += softplus_fast(dn[j]);
        neg_acc += s;
    }
    #pragma unroll
    for (int m = 32; m >= 1; m >>= 1) {
        pos_acc += __shfl_xor(pos_acc, m, 64);
        neg_acc += __shfl_xor(neg_acc, m, 64);
    }
    if ((tid & 63) == 0) {
        atomicAdd(&acc[0], pos_acc);
        atomicAdd(&acc[1], neg_acc);
    }
}

__global__ void ns_finalize_f32_kernel(const float* __restrict__ acc, float* __restrict__ out) {
    out[0] = acc[0] * (1.0f / ((float)BATCH * 8.0f));
    out[1] = acc[1] * (1.0f / ((float)BATCH * (float)NEG * 8.0f));
}

extern "C" void kernel_launch(void* const* d_in, const int* in_sizes, int n_in,
                              void* d_out, int out_size, void* d_ws, size_t ws_size,
                              hipStream_t stream) {
    const int*   tgt  = (const int*)d_in[0];
    const int*   ctx  = (const int*)d_in[1];
    const int*   negw = (const int*)d_in[2];
    const float* iemb = (const float*)d_in[3];
    const float* oemb = (const float*)d_in[4];
    float* out = (float*)d_out;
    float* acc = (float*)d_ws;

    if (ws_size >= WS_NEEDED) {
        f16* iembH = (f16*)((char*)d_ws + 256);
        f16* oembH = (f16*)((char*)d_ws + 256 + TABLE_HALF_BYTES);
        ns_init_kernel<<<1, 1, 0, stream>>>(acc);
        ns_convert_kernel<<<2048, 256, 0, stream>>>(iemb, oemb, iembH, oembH);
        ns_loss_h_kernel<<<NBLOCK, NTHREADS, 0, stream>>>(tgt, ctx, negw, iembH, oembH, acc);
        ns_finalize_h_kernel<<<1, 1, 0, stream>>>(acc, out);
    } else {
        ns_init_kernel<<<1, 1, 0, stream>>>(acc);
        ns_loss_f32_kernel<<<2048, 256, 0, stream>>>(tgt, ctx, negw, iemb, oemb, acc);
        ns_finalize_f32_kernel<<<1, 1, 0, stream>>>(acc, out);
    }
}